// Round 3
// baseline (2719.649 us; speedup 1.0000x reference)
//
#include <hip/hip_runtime.h>

#define N_ROWS 200000
#define D_IN   512
#define D_HID  2048
#define BM     128                       // rows per block (4 waves x 32 rows)
#define NBLK   ((N_ROWS + BM - 1) / BM)  // 1563
#define JT     16                        // j-tile width (hidden units per iter)
#define NJT    (D_HID / JT)              // 128
#define NCB    ((N_ROWS + 255) / 256)    // 782 count/scatter blocks

typedef short  bf16x8 __attribute__((ext_vector_type(8)));
typedef float  f32x4  __attribute__((ext_vector_type(4)));
typedef unsigned short u16x4 __attribute__((ext_vector_type(4)));

// workspace layout (bytes)
#define CNT_OFS  0                        // int cnt[4]
#define BC_OFS   16                       // int bc[NCB][4]
#define BASE_OFS (BC_OFS + NCB * 16)      // int bases[NCB][4]
#define PERM_OFS (BASE_OFS + NCB * 16)    // int perm[3][N_ROWS]
#define W1_OFS   (((PERM_OFS + 3 * N_ROWS * 4) + 15) & ~15)

__device__ __forceinline__ unsigned short f2bf(float f) {
  unsigned u = __builtin_bit_cast(unsigned, f);
  u += 0x7fffu + ((u >> 16) & 1u);               // round-to-nearest-even
  return (unsigned short)(u >> 16);
}

// ---------------- prep: convert 3x W1 fp32 -> bf16 ----------------
__global__ void k_convert(const float* __restrict__ w1c, const float* __restrict__ w1h,
                          const float* __restrict__ w1o, unsigned short* __restrict__ dst) {
  const int per = (D_HID * D_IN) / 4;            // 262144 float4 groups per matrix
  int i = blockIdx.x * 256 + threadIdx.x;
  if (i >= 3 * per) return;
  int t = i / per, r = i - t * per;
  const float* src = (t == 0) ? w1c : ((t == 1) ? w1h : w1o);
  f32x4 v = *(const f32x4*)(src + r * 4);
  u16x4 o;
  o[0] = f2bf(v[0]); o[1] = f2bf(v[1]); o[2] = f2bf(v[2]); o[3] = f2bf(v[3]);
  *(u16x4*)(dst + (size_t)i * 4) = o;
}

// ---------------- routing: count -> scan -> scatter (NO global atomics) ----------------
__global__ void k_count(const int* __restrict__ an, int* __restrict__ bc) {
  int b = blockIdx.x;
  int i = b * 256 + threadIdx.x;
  int lane = threadIdx.x & 63, w = threadIdx.x >> 6;
  int t = -1;
  if (i < N_ROWS) { int a = an[i]; t = (a == 6) ? 0 : ((a == 1) ? 1 : 2); }
  __shared__ int wc[4][3];
#pragma unroll
  for (int tt = 0; tt < 3; ++tt) {
    unsigned long long m = __ballot(t == tt);
    if (lane == 0) wc[w][tt] = (int)__popcll(m);
  }
  __syncthreads();
  if (threadIdx.x < 3) {
    int tt = threadIdx.x;
    bc[b * 4 + tt] = wc[0][tt] + wc[1][tt] + wc[2][tt] + wc[3][tt];
  }
}

__global__ void k_scan(const int* __restrict__ bc, int* __restrict__ bases,
                       int* __restrict__ cnt) {
  __shared__ int s[1024];
  int i = threadIdx.x;
  for (int t = 0; t < 3; ++t) {
    int v = (i < NCB) ? bc[i * 4 + t] : 0;
    int x = v;
    s[i] = x;
    __syncthreads();
    for (int off = 1; off < 1024; off <<= 1) {
      int a = (i >= off) ? s[i - off] : 0;
      __syncthreads();
      x += a;
      s[i] = x;
      __syncthreads();
    }
    if (i < NCB) bases[i * 4 + t] = x - v;       // exclusive prefix
    if (i == 0) cnt[t] = s[1023];                // total
    __syncthreads();
  }
}

__global__ void k_scatter(const int* __restrict__ an, const int* __restrict__ bases,
                          int* __restrict__ perm) {
  int b = blockIdx.x;
  int i = b * 256 + threadIdx.x;
  int lane = threadIdx.x & 63, w = threadIdx.x >> 6;
  int t = -1;
  if (i < N_ROWS) { int a = an[i]; t = (a == 6) ? 0 : ((a == 1) ? 1 : 2); }
  __shared__ int wc[4][3];
  unsigned long long mm[3];
#pragma unroll
  for (int tt = 0; tt < 3; ++tt) {
    mm[tt] = __ballot(t == tt);
    if (lane == 0) wc[w][tt] = (int)__popcll(mm[tt]);
  }
  __syncthreads();
  if (t >= 0) {
    unsigned long long m = mm[t];
    int off = (int)__popcll(m & ((1ull << lane) - 1ull));
    int pre = 0;
#pragma unroll
    for (int ww = 0; ww < 3; ++ww) if (ww < w) pre += wc[ww][t];
    perm[t * N_ROWS + bases[b * 4 + t] + pre + off] = i;
  }
}

// ---------------- main: grouped MFMA GEMM + fused layer-2 epilogue ----------------
// Wave tile: 32 rows (A fully in regs, K=512) x 16 hidden cols per j-iter.
// LDS W1 tile layout is k-group-major: group ks (1 KB) holds chunks
// [row lj][kq] at slot lj*4+kq, so every wave read is a permutation of one
// contiguous 1 KB group -> bank-balanced by construction. Stage pattern
// writes the same layout (global_load_lds dest = uniform base + lane*16).
__global__ __launch_bounds__(256, 3) void k_mlp(
    const float* __restrict__ x,
    const unsigned short* __restrict__ w1base,
    const int* __restrict__ perm, const int* __restrict__ cnt,
    const float* __restrict__ b1c, const float* __restrict__ b1h, const float* __restrict__ b1o,
    const float* __restrict__ w2c, const float* __restrict__ w2h, const float* __restrict__ w2o,
    const float* __restrict__ b2c, const float* __restrict__ b2h, const float* __restrict__ b2o,
    float* __restrict__ out) {
  int bid = blockIdx.x;
  int t = bid / NBLK, m = bid - t * NBLK;
  int cnt_t = cnt[t];
  int base_row = m * BM;
  if (base_row >= cnt_t) return;

  const unsigned short* w1 = w1base + (size_t)t * (D_HID * D_IN);
  const float* b1 = (t == 0) ? b1c : ((t == 1) ? b1h : b1o);
  const float* w2 = (t == 0) ? w2c : ((t == 1) ? w2h : w2o);
  const float* b2 = (t == 0) ? b2c : ((t == 1) ? b2h : b2o);
  const int* permt = perm + t * N_ROWS;

  const int tid = threadIdx.x;
  const int w = tid >> 6, lane = tid & 63;
  const int lj = lane & 15, lq = lane >> 4;

  __shared__ __align__(16) unsigned short smem[2 * JT * D_IN];  // 2 x 16 KB

  // ---- A fragments: 32 rows/wave, full K in registers (128 VGPR) ----
  int rowg[2];
#pragma unroll
  for (int rf = 0; rf < 2; ++rf) {
    int idx = base_row + w * 32 + rf * 16 + lj;
    idx = min(idx, cnt_t - 1);                   // clamp tail rows (store predicated later)
    rowg[rf] = permt[idx];
  }
  bf16x8 afrag[2][16];
#pragma unroll
  for (int rf = 0; rf < 2; ++rf) {
    const float* xr = x + (size_t)rowg[rf] * D_IN + lq * 8;
#pragma unroll
    for (int ks = 0; ks < 16; ++ks) {
      f32x4 v0 = *(const f32x4*)(xr + ks * 32);
      f32x4 v1 = *(const f32x4*)(xr + ks * 32 + 4);
      bf16x8 a;
      a[0] = (short)f2bf(v0[0]); a[1] = (short)f2bf(v0[1]);
      a[2] = (short)f2bf(v0[2]); a[3] = (short)f2bf(v0[3]);
      a[4] = (short)f2bf(v1[0]); a[5] = (short)f2bf(v1[1]);
      a[6] = (short)f2bf(v1[2]); a[7] = (short)f2bf(v1[3]);
      afrag[rf][ks] = a;
    }
  }

  // stage one W1 j-tile (16 rows x 512 k, bf16) into LDS buffer `buf`,
  // k-group-major: LDS chunk (g, l) <- W1 row (j0 + l>>2), chunk g*4 + (l&3)
  auto stage = [&](int buf, int j0) {
#pragma unroll
    for (int c = 0; c < 4; ++c) {
      int g = w * 4 + c;                         // k-group 0..15
      const unsigned short* src =
          w1 + (size_t)(j0 + (lane >> 2)) * D_IN + (g * 4 + (lane & 3)) * 8;
      unsigned short* dst = &smem[buf * (JT * D_IN) + g * 512];  // uniform; HW adds lane*16B
      __builtin_amdgcn_global_load_lds(
          (const __attribute__((address_space(1))) unsigned int*)src,
          (__attribute__((address_space(3))) unsigned int*)dst, 16, 0, 0);
    }
  };

  stage(0, 0);
  f32x4 osum0 = {0.f, 0.f, 0.f, 0.f}, osum1 = {0.f, 0.f, 0.f, 0.f};
  // per-ks read offset: group base + chunk (lj*4 + lq), 16B chunks
  const unsigned short* bbase = &smem[(lj * 4 + lq) * 8];
  float b1v = b1[lj], w2v = w2[lj];
  __syncthreads();

  for (int jt = 0; jt < NJT; ++jt) {
    int cur = jt & 1;
    if (jt + 1 < NJT) stage(cur ^ 1, (jt + 1) * JT);
    float b1n = 0.f, w2n = 0.f;
    if (jt + 1 < NJT) { b1n = b1[(jt + 1) * JT + lj]; w2n = w2[(jt + 1) * JT + lj]; }
    f32x4 acc0 = {0.f, 0.f, 0.f, 0.f}, acc1 = {0.f, 0.f, 0.f, 0.f};
    const unsigned short* bb = bbase + cur * (JT * D_IN);
    __builtin_amdgcn_s_setprio(1);
#pragma unroll
    for (int ks = 0; ks < 16; ++ks) {
      bf16x8 bfrag = *(const bf16x8*)(bb + ks * 512);
      acc0 = __builtin_amdgcn_mfma_f32_16x16x32_bf16(afrag[0][ks], bfrag, acc0, 0, 0, 0);
      acc1 = __builtin_amdgcn_mfma_f32_16x16x32_bf16(afrag[1][ks], bfrag, acc1, 0, 0, 0);
    }
    __builtin_amdgcn_s_setprio(0);
    // fused layer 2: out += relu(h + b1) * w2, accumulated per-lane over j
#pragma unroll
    for (int q = 0; q < 4; ++q) {
      osum0[q] = fmaf(fmaxf(acc0[q] + b1v, 0.f), w2v, osum0[q]);
      osum1[q] = fmaf(fmaxf(acc1[q] + b1v, 0.f), w2v, osum1[q]);
    }
    b1v = b1n; w2v = w2n;
    __syncthreads();
  }

  // reduce across the 16 col-lanes (C layout: col=lane&15, row=(lane>>4)*4+q)
  float b2v = b2[0];
#pragma unroll
  for (int rf = 0; rf < 2; ++rf) {
    f32x4 os = rf ? osum1 : osum0;
#pragma unroll
    for (int q = 0; q < 4; ++q) {
      float v = os[q];
      v += __shfl_xor(v, 1, 64);
      v += __shfl_xor(v, 2, 64);
      v += __shfl_xor(v, 4, 64);
      v += __shfl_xor(v, 8, 64);
      int idx = base_row + w * 32 + rf * 16 + lq * 4 + q;
      if (lj == 0 && idx < cnt_t) out[permt[idx]] = v + b2v;
    }
  }
}

extern "C" void kernel_launch(void* const* d_in, const int* in_sizes, int n_in,
                              void* d_out, int out_size, void* d_ws, size_t ws_size,
                              hipStream_t stream) {
  const float* x  = (const float*)d_in[0];
  const int* an   = (const int*)d_in[1];
  const float* w1c = (const float*)d_in[2],  *b1c = (const float*)d_in[3];
  const float* w2c = (const float*)d_in[4],  *b2c = (const float*)d_in[5];
  const float* w1h = (const float*)d_in[6],  *b1h = (const float*)d_in[7];
  const float* w2h = (const float*)d_in[8],  *b2h = (const float*)d_in[9];
  const float* w1o = (const float*)d_in[10], *b1o = (const float*)d_in[11];
  const float* w2o = (const float*)d_in[12], *b2o = (const float*)d_in[13];
  float* out = (float*)d_out;

  int* cnt   = (int*)((char*)d_ws + CNT_OFS);
  int* bc    = (int*)((char*)d_ws + BC_OFS);
  int* bases = (int*)((char*)d_ws + BASE_OFS);
  int* perm  = (int*)((char*)d_ws + PERM_OFS);
  unsigned short* w1bf = (unsigned short*)((char*)d_ws + W1_OFS);

  k_convert<<<(3 * (D_HID * D_IN) / 4 + 255) / 256, 256, 0, stream>>>(w1c, w1h, w1o, w1bf);
  k_count<<<NCB, 256, 0, stream>>>(an, bc);
  k_scan<<<1, 1024, 0, stream>>>(bc, bases, cnt);
  k_scatter<<<NCB, 256, 0, stream>>>(an, bases, perm);
  k_mlp<<<3 * NBLK, 256, 0, stream>>>(x, w1bf, perm, cnt,
                                      b1c, b1h, b1o, w2c, w2h, w2o,
                                      b2c, b2h, b2o, out);
}

// Round 7
// 1000.423 us; speedup vs baseline: 2.7185x; 2.7185x over previous
//
#include <hip/hip_runtime.h>
#include <hip/hip_bf16.h>

#define N_ROWS 200000
#define D_IN   512
#define D_HID  2048
#define BM     128                       // rows per block (4 waves x 32 rows)
#define NBLK   ((N_ROWS + BM - 1) / BM)  // 1563
#define JT     16                        // j-tile width (hidden units per iter)
#define NJT    (D_HID / JT)              // 128
#define NCB    ((N_ROWS + 255) / 256)    // 782 count/scatter blocks

typedef short  bf16x8 __attribute__((ext_vector_type(8)));
typedef float  f32x4  __attribute__((ext_vector_type(4)));
typedef unsigned short u16x4 __attribute__((ext_vector_type(4)));

// workspace layout (bytes)
#define CNT_OFS  0                        // int cnt[4]
#define BC_OFS   16                       // int bc[NCB][4]
#define BASE_OFS (BC_OFS + NCB * 16)      // int bases[NCB][4]
#define PERM_OFS (BASE_OFS + NCB * 16)    // int perm[3][N_ROWS]
#define W1_OFS   (((PERM_OFS + 3 * N_ROWS * 4) + 15) & ~15)

__device__ __forceinline__ unsigned short f2bf(float f) {
  unsigned u = __builtin_bit_cast(unsigned, f);
  u += 0x7fffu + ((u >> 16) & 1u);               // round-to-nearest-even
  return (unsigned short)(u >> 16);
}

__device__ __forceinline__ unsigned cvt2(float a, float b) {
  __hip_bfloat162 h = __float22bfloat162_rn(float2{a, b});  // v_cvt_pk_bf16_f32
  unsigned r;
  __builtin_memcpy(&r, &h, 4);                   // bit_cast rejected: class type not trivially copyable
  return r;
}

// ---------------- prep: convert 3x W1 fp32 -> bf16 ----------------
__global__ void k_convert(const float* __restrict__ w1c, const float* __restrict__ w1h,
                          const float* __restrict__ w1o, unsigned short* __restrict__ dst) {
  const int per = (D_HID * D_IN) / 4;            // 262144 float4 groups per matrix
  int i = blockIdx.x * 256 + threadIdx.x;
  if (i >= 3 * per) return;
  int t = i / per, r = i - t * per;
  const float* src = (t == 0) ? w1c : ((t == 1) ? w1h : w1o);
  f32x4 v = *(const f32x4*)(src + r * 4);
  u16x4 o;
  o[0] = f2bf(v[0]); o[1] = f2bf(v[1]); o[2] = f2bf(v[2]); o[3] = f2bf(v[3]);
  *(u16x4*)(dst + (size_t)i * 4) = o;
}

// ---------------- routing: count -> scan -> scatter (NO global atomics) ----------------
__global__ void k_count(const int* __restrict__ an, int* __restrict__ bc) {
  int b = blockIdx.x;
  int i = b * 256 + threadIdx.x;
  int lane = threadIdx.x & 63, w = threadIdx.x >> 6;
  int t = -1;
  if (i < N_ROWS) { int a = an[i]; t = (a == 6) ? 0 : ((a == 1) ? 1 : 2); }
  __shared__ int wc[4][3];
#pragma unroll
  for (int tt = 0; tt < 3; ++tt) {
    unsigned long long m = __ballot(t == tt);
    if (lane == 0) wc[w][tt] = (int)__popcll(m);
  }
  __syncthreads();
  if (threadIdx.x < 3) {
    int tt = threadIdx.x;
    bc[b * 4 + tt] = wc[0][tt] + wc[1][tt] + wc[2][tt] + wc[3][tt];
  }
}

__global__ void k_scan(const int* __restrict__ bc, int* __restrict__ bases,
                       int* __restrict__ cnt) {
  __shared__ int s[1024];
  int i = threadIdx.x;
  for (int t = 0; t < 3; ++t) {
    int v = (i < NCB) ? bc[i * 4 + t] : 0;
    int x = v;
    s[i] = x;
    __syncthreads();
    for (int off = 1; off < 1024; off <<= 1) {
      int a = (i >= off) ? s[i - off] : 0;
      __syncthreads();
      x += a;
      s[i] = x;
      __syncthreads();
    }
    if (i < NCB) bases[i * 4 + t] = x - v;       // exclusive prefix
    if (i == 0) cnt[t] = s[1023];                // total
    __syncthreads();
  }
}

__global__ void k_scatter(const int* __restrict__ an, const int* __restrict__ bases,
                          int* __restrict__ perm) {
  int b = blockIdx.x;
  int i = b * 256 + threadIdx.x;
  int lane = threadIdx.x & 63, w = threadIdx.x >> 6;
  int t = -1;
  if (i < N_ROWS) { int a = an[i]; t = (a == 6) ? 0 : ((a == 1) ? 1 : 2); }
  __shared__ int wc[4][3];
  unsigned long long mm[3];
#pragma unroll
  for (int tt = 0; tt < 3; ++tt) {
    mm[tt] = __ballot(t == tt);
    if (lane == 0) wc[w][tt] = (int)__popcll(mm[tt]);
  }
  __syncthreads();
  if (t >= 0) {
    unsigned long long m = mm[t];
    int off = (int)__popcll(m & ((1ull << lane) - 1ull));
    int pre = 0;
#pragma unroll
    for (int ww = 0; ww < 3; ++ww) if (ww < w) pre += wc[ww][t];
    perm[t * N_ROWS + bases[b * 4 + t] + pre + off] = i;
  }
}

// ---------------- main: grouped MFMA GEMM + fused layer-2 epilogue ----------------
// Wave tile: 32 rows (A fully in regs, K=512) x 16 hidden cols per j-iter.
// LDS layout per buffer: 16 groups (g) x 1024 B. Group g slot s (16 B)
// holds W1 row (j0 + (s&15)), k-chunk (g*4 + (s>>4)). Read for MFMA k-step
// ks: lane l needs (row l&15, chunk ks*4 + (l>>4)) -> slot l. Lane l reads
// byte ks*1024 + l*16: consecutive lanes, consecutive addresses ->
// conflict-free under any HW phasing. Stage source permuted to match
// (global_load_lds dest is linear: uniform base + lane*16; rule #21).
__global__ __launch_bounds__(256, 2) void k_mlp(
    const float* __restrict__ x,
    const unsigned short* __restrict__ w1base,
    const int* __restrict__ perm, const int* __restrict__ cnt,
    const float* __restrict__ b1c, const float* __restrict__ b1h, const float* __restrict__ b1o,
    const float* __restrict__ w2c, const float* __restrict__ w2h, const float* __restrict__ w2o,
    const float* __restrict__ b2c, const float* __restrict__ b2h, const float* __restrict__ b2o,
    float* __restrict__ out) {
  int bid = blockIdx.x;
  int t = bid / NBLK, m = bid - t * NBLK;
  int cnt_t = cnt[t];
  int base_row = m * BM;
  if (base_row >= cnt_t) return;

  const unsigned short* w1 = w1base + (size_t)t * (D_HID * D_IN);
  const float* b1 = (t == 0) ? b1c : ((t == 1) ? b1h : b1o);
  const float* w2 = (t == 0) ? w2c : ((t == 1) ? w2h : w2o);
  const float* b2 = (t == 0) ? b2c : ((t == 1) ? b2h : b2o);
  const int* permt = perm + t * N_ROWS;

  const int tid = threadIdx.x;
  const int w = tid >> 6, lane = tid & 63;
  const int lj = lane & 15, lq = lane >> 4;

  __shared__ __align__(16) unsigned short smem[2 * JT * D_IN];  // 2 x 16 KB

  // ---- A fragments: 32 rows/wave, full K in registers (128 VGPR) ----
  int rowg[2];
#pragma unroll
  for (int rf = 0; rf < 2; ++rf) {
    int idx = base_row + w * 32 + rf * 16 + lj;
    idx = min(idx, cnt_t - 1);                   // clamp tail rows (store predicated later)
    rowg[rf] = permt[idx];
  }
  bf16x8 afrag[2][16];
#pragma unroll
  for (int rf = 0; rf < 2; ++rf) {
    const float* xr = x + (size_t)rowg[rf] * D_IN + lq * 8;
#pragma unroll
    for (int ks = 0; ks < 16; ++ks) {
      f32x4 v0 = *(const f32x4*)(xr + ks * 32);
      f32x4 v1 = *(const f32x4*)(xr + ks * 32 + 4);
      bf16x8 a;
      unsigned* ap = (unsigned*)&a;
      ap[0] = cvt2(v0[0], v0[1]);
      ap[1] = cvt2(v0[2], v0[3]);
      ap[2] = cvt2(v1[0], v1[1]);
      ap[3] = cvt2(v1[2], v1[3]);
      afrag[rf][ks] = a;
    }
  }

  // stage one W1 j-tile (16 rows x 512 k bf16) into LDS buffer `buf`:
  // group g slot (lane) <- W1 row j0+(lane&15), k-chunk g*4+(lane>>4)
  auto stage = [&](int buf, int j0) {
#pragma unroll
    for (int c = 0; c < 4; ++c) {
      int g = w * 4 + c;                         // k-group 0..15
      const unsigned short* src =
          w1 + (size_t)(j0 + (lane & 15)) * D_IN + (g * 4 + (lane >> 4)) * 8;
      unsigned short* dst = &smem[buf * (JT * D_IN) + g * 512];  // uniform; HW adds lane*16B
      __builtin_amdgcn_global_load_lds(
          (const __attribute__((address_space(1))) unsigned int*)src,
          (__attribute__((address_space(3))) unsigned int*)dst, 16, 0, 0);
    }
  };

  stage(0, 0);
  f32x4 osum0 = {0.f, 0.f, 0.f, 0.f}, osum1 = {0.f, 0.f, 0.f, 0.f};
  // per-ks read: slot `lane` of group ks (16 B chunks)
  const unsigned short* bbase = &smem[lane * 8];
  float b1v = b1[lj], w2v = w2[lj];
  __syncthreads();

  for (int jt = 0; jt < NJT; ++jt) {
    int cur = jt & 1;
    if (jt + 1 < NJT) stage(cur ^ 1, (jt + 1) * JT);
    float b1n = 0.f, w2n = 0.f;
    if (jt + 1 < NJT) { b1n = b1[(jt + 1) * JT + lj]; w2n = w2[(jt + 1) * JT + lj]; }
    f32x4 acc0 = {0.f, 0.f, 0.f, 0.f}, acc1 = {0.f, 0.f, 0.f, 0.f};
    const unsigned short* bb = bbase + cur * (JT * D_IN);
    __builtin_amdgcn_s_setprio(1);
#pragma unroll
    for (int ks = 0; ks < 16; ++ks) {
      bf16x8 bfrag = *(const bf16x8*)(bb + ks * 512);
      acc0 = __builtin_amdgcn_mfma_f32_16x16x32_bf16(afrag[0][ks], bfrag, acc0, 0, 0, 0);
      acc1 = __builtin_amdgcn_mfma_f32_16x16x32_bf16(afrag[1][ks], bfrag, acc1, 0, 0, 0);
    }
    __builtin_amdgcn_s_setprio(0);
    // fused layer 2: out += relu(h + b1) * w2, accumulated per-lane over j
#pragma unroll
    for (int q = 0; q < 4; ++q) {
      osum0[q] = fmaf(fmaxf(acc0[q] + b1v, 0.f), w2v, osum0[q]);
      osum1[q] = fmaf(fmaxf(acc1[q] + b1v, 0.f), w2v, osum1[q]);
    }
    b1v = b1n; w2v = w2n;
    __syncthreads();
  }

  // reduce across the 16 col-lanes (C layout: col=lane&15, row=(lane>>4)*4+q)
  float b2v = b2[0];
#pragma unroll
  for (int rf = 0; rf < 2; ++rf) {
    f32x4 os = rf ? osum1 : osum0;
#pragma unroll
    for (int q = 0; q < 4; ++q) {
      float v = os[q];
      v += __shfl_xor(v, 1, 64);
      v += __shfl_xor(v, 2, 64);
      v += __shfl_xor(v, 4, 64);
      v += __shfl_xor(v, 8, 64);
      int idx = base_row + w * 32 + rf * 16 + lq * 4 + q;
      if (lj == 0 && idx < cnt_t) out[permt[idx]] = v + b2v;
    }
  }
}

extern "C" void kernel_launch(void* const* d_in, const int* in_sizes, int n_in,
                              void* d_out, int out_size, void* d_ws, size_t ws_size,
                              hipStream_t stream) {
  const float* x  = (const float*)d_in[0];
  const int* an   = (const int*)d_in[1];
  const float* w1c = (const float*)d_in[2],  *b1c = (const float*)d_in[3];
  const float* w2c = (const float*)d_in[4],  *b2c = (const float*)d_in[5];
  const float* w1h = (const float*)d_in[6],  *b1h = (const float*)d_in[7];
  const float* w2h = (const float*)d_in[8],  *b2h = (const float*)d_in[9];
  const float* w1o = (const float*)d_in[10], *b1o = (const float*)d_in[11];
  const float* w2o = (const float*)d_in[12], *b2o = (const float*)d_in[13];
  float* out = (float*)d_out;

  int* cnt   = (int*)((char*)d_ws + CNT_OFS);
  int* bc    = (int*)((char*)d_ws + BC_OFS);
  int* bases = (int*)((char*)d_ws + BASE_OFS);
  int* perm  = (int*)((char*)d_ws + PERM_OFS);
  unsigned short* w1bf = (unsigned short*)((char*)d_ws + W1_OFS);

  k_convert<<<(3 * (D_HID * D_IN) / 4 + 255) / 256, 256, 0, stream>>>(w1c, w1h, w1o, w1bf);
  k_count<<<NCB, 256, 0, stream>>>(an, bc);
  k_scan<<<1, 1024, 0, stream>>>(bc, bases, cnt);
  k_scatter<<<NCB, 256, 0, stream>>>(an, bases, perm);
  k_mlp<<<3 * NBLK, 256, 0, stream>>>(x, w1bf, perm, cnt,
                                      b1c, b1h, b1o, w2c, w2h, w2o,
                                      b2c, b2h, b2o, out);
}